// Round 1
// baseline (285.323 us; speedup 1.0000x reference)
//
#include <hip/hip_runtime.h>

typedef _Float16 half8v __attribute__((ext_vector_type(8)));
typedef _Float16 half4v __attribute__((ext_vector_type(4)));
typedef float f32x4 __attribute__((ext_vector_type(4)));

constexpr float INV4096 = 1.0f / 4096.0f;
constexpr float ALPHA = 10.0f;

__device__ __forceinline__ f32x4 mfma16(half8v a, half8v b, f32x4 c_) {
  return __builtin_amdgcn_mfma_f32_16x16x32_f16(a, b, c_, 0, 0, 0);
}

// LDS map (48 KB):
//  [0,16384)      B buf0: hi 64x128B at +0, lo at +8192
//  [16384,32768)  B buf1: hi at +16384, lo at +24576
//  [0,16384)      (epilogue alias) clean_lds: wave w at w*4096, 16 rows x 256B
//  [32768,49152)  w_noise split [e][k]: hi at +32768, lo at +40960
__global__ __launch_bounds__(256, 2) void topk_gating(
    const float *__restrict__ X, const float *__restrict__ GW,
    const float *__restrict__ GB, const float *__restrict__ WN,
    const float *__restrict__ NZ, float *__restrict__ OUT) {
  __shared__ __align__(16) char lds[49152];
  const int tid = threadIdx.x;
  const int lane = tid & 63;
  const int wv = tid >> 6;
  const int q = lane >> 4;   // 0..3
  const int c = lane & 15;   // 0..15
  const int waveRow = blockIdx.x * 64 + wv * 16;

  // per-thread B staging coords: thread covers float4s idx4 = tid + i*256
  const int bE0 = tid >> 4;  // expert row base (+16*i)
  const int bCC = tid & 15;  // float4 column within 64-k chunk

  // ---- stage w_noise, split + transposed to [e][k] halves ----
#pragma unroll
  for (int i = 0; i < 4; ++i) {
    int idx4 = tid + i * 256;
    int k = idx4 >> 4;
    int e0 = (idx4 & 15) << 2;
    f32x4 v = *reinterpret_cast<const f32x4 *>(WN + k * 64 + e0);
#pragma unroll
    for (int j = 0; j < 4; ++j) {
      int e = e0 + j;
      float vv = v[j];
      _Float16 hh = (_Float16)vv;
      _Float16 ll = (_Float16)((vv - (float)hh) * 4096.0f);
      int off = e * 128 + ((((k >> 3) ^ (e & 7))) << 4) + ((k & 7) << 1);
      *reinterpret_cast<_Float16 *>(lds + 32768 + off) = hh;
      *reinterpret_cast<_Float16 *>(lds + 40960 + off) = ll;
    }
  }

  f32x4 accH[4] = {};
  f32x4 accX[4] = {};
  f32x4 aCur[4], aNxt[4], bCur[4], bNxt[4];

  const float *xBase = X + (size_t)(waveRow + c) * 1024 + q * 8;
  aCur[0] = *(const f32x4 *)(xBase + 0);
  aCur[1] = *(const f32x4 *)(xBase + 4);
  aCur[2] = *(const f32x4 *)(xBase + 32);
  aCur[3] = *(const f32x4 *)(xBase + 36);
#pragma unroll
  for (int i = 0; i < 4; ++i)
    bCur[i] = *(const f32x4 *)(GW + (size_t)(bE0 + 16 * i) * 1024 + bCC * 4);
  // write B chunk 0 into buf0
#pragma unroll
  for (int i = 0; i < 4; ++i) {
    int e = bE0 + 16 * i;
    half4v h, l;
#pragma unroll
    for (int j = 0; j < 4; ++j) {
      float vv = bCur[i][j];
      _Float16 hh = (_Float16)vv;
      h[j] = hh;
      l[j] = (_Float16)((vv - (float)hh) * 4096.0f);
    }
    int off = e * 128 + ((((bCC >> 1) ^ (e & 7))) << 4) + ((bCC & 1) << 3);
    *reinterpret_cast<half4v *>(lds + off) = h;
    *reinterpret_cast<half4v *>(lds + 8192 + off) = l;
  }
  __syncthreads();

  for (int kc = 0; kc < 16; ++kc) {
    if (kc < 15) {
      const float *xb = xBase + (kc + 1) * 64;
      aNxt[0] = *(const f32x4 *)(xb + 0);
      aNxt[1] = *(const f32x4 *)(xb + 4);
      aNxt[2] = *(const f32x4 *)(xb + 32);
      aNxt[3] = *(const f32x4 *)(xb + 36);
#pragma unroll
      for (int i = 0; i < 4; ++i)
        bNxt[i] = *(const f32x4 *)(GW + (size_t)(bE0 + 16 * i) * 1024 +
                                   (kc + 1) * 64 + bCC * 4);
    }
    const int buf = (kc & 1) * 16384;
#pragma unroll
    for (int ks = 0; ks < 2; ++ks) {
      half8v ah, al;
#pragma unroll
      for (int j = 0; j < 8; ++j) {
        float xv = aCur[ks * 2 + (j >> 2)][j & 3];
        _Float16 hh = (_Float16)xv;
        ah[j] = hh;
        al[j] = (_Float16)((xv - (float)hh) * 4096.0f);
      }
#pragma unroll
      for (int t = 0; t < 4; ++t) {
        int e = t * 16 + c;
        int off = buf + e * 128 + ((((ks * 4 + q) ^ (e & 7))) << 4);
        half8v bh = *reinterpret_cast<half8v *>(lds + off);
        half8v bl = *reinterpret_cast<half8v *>(lds + 8192 + off);
        accH[t] = mfma16(ah, bh, accH[t]);
        accX[t] = mfma16(ah, bl, accX[t]);
        accX[t] = mfma16(al, bh, accX[t]);
      }
    }
    if (kc < 15) {
      const int wbuf = ((kc + 1) & 1) * 16384;
#pragma unroll
      for (int i = 0; i < 4; ++i) {
        int e = bE0 + 16 * i;
        half4v h, l;
#pragma unroll
        for (int j = 0; j < 4; ++j) {
          float vv = bNxt[i][j];
          _Float16 hh = (_Float16)vv;
          h[j] = hh;
          l[j] = (_Float16)((vv - (float)hh) * 4096.0f);
        }
        int off = wbuf + e * 128 + ((((bCC >> 1) ^ (e & 7))) << 4) + ((bCC & 1) << 3);
        *reinterpret_cast<half4v *>(lds + off) = h;
        *reinterpret_cast<half4v *>(lds + 8192 + off) = l;
      }
#pragma unroll
      for (int i = 0; i < 4; ++i) aCur[i] = aNxt[i];
    }
    __syncthreads();
  }

  // ---- epilogue ----
  float cl[4][4];  // [etile][reg] ; element = (row 4q+r, expert 16t+c)
#pragma unroll
  for (int t = 0; t < 4; ++t) {
    float bs = GB[t * 16 + c];
#pragma unroll
    for (int r = 0; r < 4; ++r)
      cl[t][r] = accH[t][r] + accX[t][r] * INV4096 + bs;
  }

  float nz[4][4];
#pragma unroll
  for (int t = 0; t < 4; ++t)
#pragma unroll
    for (int r = 0; r < 4; ++r)
      nz[t][r] = NZ[(size_t)(waveRow + 4 * q + r) * 64 + t * 16 + c];

  // write clean into per-wave LDS region (aliases dead B buf0), swizzled
  char *cb = lds + wv * 4096;
#pragma unroll
  for (int t = 0; t < 4; ++t)
#pragma unroll
    for (int r = 0; r < 4; ++r) {
      int row = 4 * q + r;
      int colf = t * 16 + c;
      int off = row * 256 + ((((colf >> 2) ^ row)) << 4) + ((colf & 3) << 2);
      *reinterpret_cast<float *>(cb + off) = cl[t][r];
    }
  __syncthreads();

  // phase 2: raw = clean @ w_noise  (split-fp16 MFMA, K=64)
  f32x4 rH[4] = {};
  f32x4 rX[4] = {};
#pragma unroll
  for (int ks = 0; ks < 2; ++ks) {
    int slot0 = ks * 8 + q * 2;
    f32x4 a0 = *reinterpret_cast<f32x4 *>(cb + c * 256 + (((slot0 ^ c)) << 4));
    f32x4 a1 = *reinterpret_cast<f32x4 *>(cb + c * 256 + ((((slot0 + 1) ^ c)) << 4));
    half8v ah, al;
#pragma unroll
    for (int j = 0; j < 4; ++j) {
      float v = a0[j];
      _Float16 hh = (_Float16)v;
      ah[j] = hh;
      al[j] = (_Float16)((v - (float)hh) * 4096.0f);
      float v2 = a1[j];
      _Float16 h2 = (_Float16)v2;
      ah[4 + j] = h2;
      al[4 + j] = (_Float16)((v2 - (float)h2) * 4096.0f);
    }
#pragma unroll
    for (int t = 0; t < 4; ++t) {
      int e = t * 16 + c;
      int off = 32768 + e * 128 + ((((ks * 4 + q) ^ (e & 7))) << 4);
      half8v bh = *reinterpret_cast<half8v *>(lds + off);
      half8v bl = *reinterpret_cast<half8v *>(lds + 8192 + off);
      rH[t] = mfma16(ah, bh, rH[t]);
      rX[t] = mfma16(ah, bl, rX[t]);
      rX[t] = mfma16(al, bh, rX[t]);
    }
  }

  float logits[4][4];
#pragma unroll
  for (int t = 0; t < 4; ++t)
#pragma unroll
    for (int r = 0; r < 4; ++r) {
      float raw = rH[t][r] + rX[t][r] * INV4096;
      float sp = fmaxf(raw, 0.0f) + __logf(1.0f + __expf(-fabsf(raw)));
      logits[t][r] = cl[t][r] + nz[t][r] * (sp + 1e-5f);
    }

  // top-2 per row: in-lane over 4 etiles, then xor-shuffle over the 16-lane group
  float m1v[4], m2v[4];
#pragma unroll
  for (int r = 0; r < 4; ++r) {
    float v0 = logits[0][r], v1 = logits[1][r], v2 = logits[2][r], v3 = logits[3][r];
    float a = fmaxf(v0, v1), b = fminf(v0, v1);
    float d1 = fmaxf(v2, v3), d2 = fminf(v2, v3);
    float m1 = fmaxf(a, d1);
    float m2 = fmaxf(fminf(a, d1), fmaxf(b, d2));
#pragma unroll
    for (int s = 1; s <= 8; s <<= 1) {
      float om1 = __shfl_xor(m1, s, 64);
      float om2 = __shfl_xor(m2, s, 64);
      float hi = fmaxf(m1, om1);
      float lo = fminf(m1, om1);
      float sec = (m1 >= om1) ? m2 : om2;
      m2 = fmaxf(lo, sec);
      m1 = hi;
    }
    m1v[r] = m1;
    m2v[r] = m2;
  }

  // softmax(logits)
  float sme[4][4];
  float ssum[4] = {0.f, 0.f, 0.f, 0.f};
#pragma unroll
  for (int t = 0; t < 4; ++t)
#pragma unroll
    for (int r = 0; r < 4; ++r) {
      float e_ = __expf(logits[t][r] - m1v[r]);
      sme[t][r] = e_;
      ssum[r] += e_;
    }
#pragma unroll
  for (int r = 0; r < 4; ++r) {
#pragma unroll
    for (int s = 1; s <= 8; s <<= 1) ssum[r] += __shfl_xor(ssum[r], s, 64);
  }

  float outv[4][4];
#pragma unroll
  for (int r = 0; r < 4; ++r) {
    float inv = 1.0f / ssum[r];
#pragma unroll
    for (int t = 0; t < 4; ++t) {
      float sm = sme[t][r] * inv;
      float vlog = ALPHA * __logf(1.0f + sm);
      float vexp = ALPHA * (__expf(sm) - 1.0f);
      outv[t][r] = (logits[t][r] < m2v[r]) ? vlog : vexp;
    }
  }

  // gates = softmax(out)
  float gmax[4];
#pragma unroll
  for (int r = 0; r < 4; ++r) {
    float g = fmaxf(fmaxf(outv[0][r], outv[1][r]), fmaxf(outv[2][r], outv[3][r]));
#pragma unroll
    for (int s = 1; s <= 8; s <<= 1) g = fmaxf(g, __shfl_xor(g, s, 64));
    gmax[r] = g;
  }
  float gsum[4] = {0.f, 0.f, 0.f, 0.f};
#pragma unroll
  for (int t = 0; t < 4; ++t)
#pragma unroll
    for (int r = 0; r < 4; ++r) {
      float e_ = __expf(outv[t][r] - gmax[r]);
      outv[t][r] = e_;
      gsum[r] += e_;
    }
#pragma unroll
  for (int r = 0; r < 4; ++r) {
#pragma unroll
    for (int s = 1; s <= 8; s <<= 1) gsum[r] += __shfl_xor(gsum[r], s, 64);
  }
#pragma unroll
  for (int r = 0; r < 4; ++r) {
    float ginv = 1.0f / gsum[r];
    size_t rowOff = (size_t)(waveRow + 4 * q + r) * 64;
#pragma unroll
    for (int t = 0; t < 4; ++t)
      OUT[rowOff + t * 16 + c] = outv[t][r] * ginv;
  }
}

extern "C" void kernel_launch(void *const *d_in, const int *in_sizes, int n_in,
                              void *d_out, int out_size, void *d_ws,
                              size_t ws_size, hipStream_t stream) {
  const float *x = (const float *)d_in[0];
  const float *gw = (const float *)d_in[1];
  const float *gb = (const float *)d_in[2];
  const float *wn = (const float *)d_in[3];
  const float *nz = (const float *)d_in[4];
  float *out = (float *)d_out;
  const int N = in_sizes[0] / 1024;
  dim3 grid(N / 64), block(256);
  hipLaunchKernelGGL(topk_gating, grid, block, 0, stream, x, gw, gb, wn, nz, out);
}

// Round 2
// 283.309 us; speedup vs baseline: 1.0071x; 1.0071x over previous
//
#include <hip/hip_runtime.h>

typedef _Float16 half8v __attribute__((ext_vector_type(8)));
typedef float f32x4 __attribute__((ext_vector_type(4)));

constexpr float INV4096 = 1.0f / 4096.0f;
constexpr float ALPHA = 10.0f;

__device__ __forceinline__ f32x4 mfma16(half8v a, half8v b, f32x4 c_) {
  return __builtin_amdgcn_mfma_f32_16x16x32_f16(a, b, c_, 0, 0, 0);
}

__device__ __forceinline__ void dma16(const void *g, void *l) {
  __builtin_amdgcn_global_load_lds(
      (const __attribute__((address_space(1))) void *)g,
      (__attribute__((address_space(3))) void *)l, 16, 0, 0);
}

// ---- pre-split kernel: GW (64x1024 f32) and WN (64x64 f32) -> fp16 hi/lo ----
// ws image (bytes):
//   [0, 262144)        GW: 16 chunks x 16KB; chunk ck: hi[e][kk] at
//                      ck*16384 + e*128 + (((kk>>3)^(e&7))<<4) + (kk&7)*2, lo at +8192
//   [262144, 278528)   WN: same layout, single 16KB image (k = 0..63)
__global__ __launch_bounds__(256) void presplit(const float *__restrict__ GW,
                                                const float *__restrict__ WN,
                                                char *__restrict__ ws) {
  const int b = blockIdx.x;
  const int tid = threadIdx.x;
  if (b < 64) {
    int idx = b * 256 + tid;  // f32x4 index into GW
    int e = idx >> 8;
    int c4 = idx & 255;
    f32x4 v = *reinterpret_cast<const f32x4 *>(GW + (size_t)idx * 4);
#pragma unroll
    for (int j = 0; j < 4; ++j) {
      int k = c4 * 4 + j;
      float vv = v[j];
      _Float16 hh = (_Float16)vv;
      _Float16 ll = (_Float16)((vv - (float)hh) * 4096.0f);
      int ck = k >> 6, kk = k & 63;
      int off = ck * 16384 + e * 128 + ((((kk >> 3) ^ (e & 7))) << 4) + ((kk & 7) << 1);
      *reinterpret_cast<_Float16 *>(ws + off) = hh;
      *reinterpret_cast<_Float16 *>(ws + off + 8192) = ll;
    }
  } else {
    int idx = (b - 64) * 256 + tid;  // f32x4 index into WN [k][e0..e0+3]
    int k = idx >> 4;
    int e0 = (idx & 15) << 2;
    f32x4 v = *reinterpret_cast<const f32x4 *>(WN + (size_t)k * 64 + e0);
#pragma unroll
    for (int j = 0; j < 4; ++j) {
      int e = e0 + j;
      float vv = v[j];
      _Float16 hh = (_Float16)vv;
      _Float16 ll = (_Float16)((vv - (float)hh) * 4096.0f);
      int off = 262144 + e * 128 + ((((k >> 3) ^ (e & 7))) << 4) + ((k & 7) << 1);
      *reinterpret_cast<_Float16 *>(ws + off) = hh;
      *reinterpret_cast<_Float16 *>(ws + off + 8192) = ll;
    }
  }
}

// LDS map (32 KB):
//  [0,16384)      B buf0 (chunk image: hi 8K, lo 8K)     | epilogue: WN image
//  [16384,32768)  B buf1                                 | epilogue: clean, wave w at 16384+w*4096
__global__ __launch_bounds__(256, 3) void topk_gating(
    const float *__restrict__ X, const char *__restrict__ WS,
    const float *__restrict__ GB, const float *__restrict__ NZ,
    float *__restrict__ OUT) {
  __shared__ __align__(16) char lds[32768];
  const int tid = threadIdx.x;
  const int lane = tid & 63;
  const int wv = tid >> 6;
  const int q = lane >> 4;  // 0..3
  const int c = lane & 15;  // 0..15
  const int waveRow = blockIdx.x * 64 + wv * 16;

  f32x4 accH[4] = {};
  f32x4 accX[4] = {};
  f32x4 aCur[4], aNxt[4];

  const float *xBase = X + (size_t)(waveRow + c) * 1024 + q * 8;
  aCur[0] = *(const f32x4 *)(xBase + 0);
  aCur[1] = *(const f32x4 *)(xBase + 4);
  aCur[2] = *(const f32x4 *)(xBase + 32);
  aCur[3] = *(const f32x4 *)(xBase + 36);
  // stage B chunk 0 -> buf0 (linear 16KB copy, layout pre-swizzled in ws)
#pragma unroll
  for (int i = 0; i < 4; ++i)
    dma16(WS + i * 4096 + wv * 1024 + lane * 16, lds + i * 4096 + wv * 1024);
  __syncthreads();

  for (int kc = 0; kc < 16; ++kc) {
    if (kc < 15) {
      const float *xb = xBase + (kc + 1) * 64;
      aNxt[0] = *(const f32x4 *)(xb + 0);
      aNxt[1] = *(const f32x4 *)(xb + 4);
      aNxt[2] = *(const f32x4 *)(xb + 32);
      aNxt[3] = *(const f32x4 *)(xb + 36);
      const int wbuf = ((kc + 1) & 1) * 16384;
      const char *src = WS + (kc + 1) * 16384;
#pragma unroll
      for (int i = 0; i < 4; ++i)
        dma16(src + i * 4096 + wv * 1024 + lane * 16,
              lds + wbuf + i * 4096 + wv * 1024);
    }
    const int buf = (kc & 1) * 16384;
#pragma unroll
    for (int ks = 0; ks < 2; ++ks) {
      half8v ah, al;
#pragma unroll
      for (int j = 0; j < 8; ++j) {
        float xv = aCur[ks * 2 + (j >> 2)][j & 3];
        _Float16 hh = (_Float16)xv;
        ah[j] = hh;
        al[j] = (_Float16)((xv - (float)hh) * 4096.0f);
      }
#pragma unroll
      for (int t = 0; t < 4; ++t) {
        int e = t * 16 + c;
        int off = buf + e * 128 + ((((ks * 4 + q) ^ (e & 7))) << 4);
        half8v bh = *reinterpret_cast<half8v *>(lds + off);
        half8v bl = *reinterpret_cast<half8v *>(lds + off + 8192);
        accH[t] = mfma16(ah, bh, accH[t]);
        accX[t] = mfma16(ah, bl, accX[t]);
        accX[t] = mfma16(al, bh, accX[t]);
      }
    }
    if (kc < 15) {
#pragma unroll
      for (int i = 0; i < 4; ++i) aCur[i] = aNxt[i];
    }
    __syncthreads();
  }

  // ---- epilogue ----
  // issue NZ loads first (HBM latency hidden under cl compute + LDS writes)
  float nz[4][4];
#pragma unroll
  for (int t = 0; t < 4; ++t)
#pragma unroll
    for (int r = 0; r < 4; ++r)
      nz[t][r] = NZ[(size_t)(waveRow + 4 * q + r) * 64 + t * 16 + c];

  // stage WN image -> lds[0,16384) (buf0 is dead: last read kc=14, barrier passed)
#pragma unroll
  for (int i = 0; i < 4; ++i)
    dma16(WS + 262144 + i * 4096 + wv * 1024 + lane * 16,
          lds + i * 4096 + wv * 1024);

  float cl[4][4];  // [etile][reg]; element = (row 4q+r, expert 16t+c)
#pragma unroll
  for (int t = 0; t < 4; ++t) {
    float bs = GB[t * 16 + c];
#pragma unroll
    for (int r = 0; r < 4; ++r)
      cl[t][r] = accH[t][r] + accX[t][r] * INV4096 + bs;
  }

  // write clean into per-wave region of buf1 (dead after final barrier), swizzled
  char *cb = lds + 16384 + wv * 4096;
#pragma unroll
  for (int t = 0; t < 4; ++t)
#pragma unroll
    for (int r = 0; r < 4; ++r) {
      int row = 4 * q + r;
      int colf = t * 16 + c;
      int off = row * 256 + ((((colf >> 2) ^ row)) << 4) + ((colf & 3) << 2);
      *reinterpret_cast<float *>(cb + off) = cl[t][r];
    }
  __syncthreads();  // drains WN DMA + syncs clean writes

  // phase 2: raw = clean @ w_noise (split-fp16 MFMA, K=64)
  f32x4 rH[4] = {};
  f32x4 rX[4] = {};
#pragma unroll
  for (int ks = 0; ks < 2; ++ks) {
    int slot0 = ks * 8 + q * 2;
    f32x4 a0 = *reinterpret_cast<f32x4 *>(cb + c * 256 + (((slot0 ^ c)) << 4));
    f32x4 a1 = *reinterpret_cast<f32x4 *>(cb + c * 256 + ((((slot0 + 1) ^ c)) << 4));
    half8v ah, al;
#pragma unroll
    for (int j = 0; j < 4; ++j) {
      float v = a0[j];
      _Float16 hh = (_Float16)v;
      ah[j] = hh;
      al[j] = (_Float16)((v - (float)hh) * 4096.0f);
      float v2 = a1[j];
      _Float16 h2 = (_Float16)v2;
      ah[4 + j] = h2;
      al[4 + j] = (_Float16)((v2 - (float)h2) * 4096.0f);
    }
#pragma unroll
    for (int t = 0; t < 4; ++t) {
      int e = t * 16 + c;
      int off = e * 128 + ((((ks * 4 + q) ^ (e & 7))) << 4);
      half8v bh = *reinterpret_cast<half8v *>(lds + off);
      half8v bl = *reinterpret_cast<half8v *>(lds + off + 8192);
      rH[t] = mfma16(ah, bh, rH[t]);
      rX[t] = mfma16(ah, bl, rX[t]);
      rX[t] = mfma16(al, bh, rX[t]);
    }
  }

  float lg[4][4];  // [r][t]
#pragma unroll
  for (int t = 0; t < 4; ++t)
#pragma unroll
    for (int r = 0; r < 4; ++r) {
      float raw = rH[t][r] + rX[t][r] * INV4096;
      float sp = fmaxf(raw, 0.0f) + __logf(1.0f + __expf(-fabsf(raw)));
      lg[r][t] = cl[t][r] + nz[t][r] * (sp + 1e-5f);
    }

#pragma unroll
  for (int r = 0; r < 4; ++r) {
    float v0 = lg[r][0], v1 = lg[r][1], v2 = lg[r][2], v3 = lg[r][3];
    // top-2: in-lane over 4, then xor-shuffle over the 16-lane group
    float a = fmaxf(v0, v1), b_ = fminf(v0, v1);
    float d1 = fmaxf(v2, v3), d2 = fminf(v2, v3);
    float m1 = fmaxf(a, d1);
    float m2 = fmaxf(fminf(a, d1), fmaxf(b_, d2));
#pragma unroll
    for (int s = 1; s <= 8; s <<= 1) {
      float om1 = __shfl_xor(m1, s, 64);
      float om2 = __shfl_xor(m2, s, 64);
      float hi = fmaxf(m1, om1);
      float lo = fminf(m1, om1);
      float sec = (m1 >= om1) ? m2 : om2;
      m2 = fmaxf(lo, sec);
      m1 = hi;
    }
    // softmax(logits)
    float se[4], ssum = 0.f;
#pragma unroll
    for (int t = 0; t < 4; ++t) {
      se[t] = __expf(lg[r][t] - m1);
      ssum += se[t];
    }
#pragma unroll
    for (int s = 1; s <= 8; s <<= 1) ssum += __shfl_xor(ssum, s, 64);
    float inv = 1.0f / ssum;
    float ov[4];
#pragma unroll
    for (int t = 0; t < 4; ++t) {
      float sm = se[t] * inv;
      float vlog = ALPHA * __logf(1.0f + sm);
      float vexp = ALPHA * (__expf(sm) - 1.0f);
      ov[t] = (lg[r][t] < m2) ? vlog : vexp;
    }
    // gates = softmax(out)
    float g = fmaxf(fmaxf(ov[0], ov[1]), fmaxf(ov[2], ov[3]));
#pragma unroll
    for (int s = 1; s <= 8; s <<= 1) g = fmaxf(g, __shfl_xor(g, s, 64));
    float gsum = 0.f;
#pragma unroll
    for (int t = 0; t < 4; ++t) {
      ov[t] = __expf(ov[t] - g);
      gsum += ov[t];
    }
#pragma unroll
    for (int s = 1; s <= 8; s <<= 1) gsum += __shfl_xor(gsum, s, 64);
    float ginv = 1.0f / gsum;
    size_t rowOff = (size_t)(waveRow + 4 * q + r) * 64;
#pragma unroll
    for (int t = 0; t < 4; ++t)
      OUT[rowOff + t * 16 + c] = ov[t] * ginv;
  }
}

extern "C" void kernel_launch(void *const *d_in, const int *in_sizes, int n_in,
                              void *d_out, int out_size, void *d_ws,
                              size_t ws_size, hipStream_t stream) {
  const float *x = (const float *)d_in[0];
  const float *gw = (const float *)d_in[1];
  const float *gb = (const float *)d_in[2];
  const float *wn = (const float *)d_in[3];
  const float *nz = (const float *)d_in[4];
  float *out = (float *)d_out;
  char *ws = (char *)d_ws;
  const int N = in_sizes[0] / 1024;

  hipLaunchKernelGGL(presplit, dim3(68), dim3(256), 0, stream, gw, wn, ws);
  hipLaunchKernelGGL(topk_gating, dim3(N / 64), dim3(256), 0, stream, x, ws,
                     gb, nz, out);
}

// Round 3
// 274.261 us; speedup vs baseline: 1.0403x; 1.0330x over previous
//
#include <hip/hip_runtime.h>

typedef _Float16 half8v __attribute__((ext_vector_type(8)));
typedef float f32x4 __attribute__((ext_vector_type(4)));

constexpr float INV4096 = 1.0f / 4096.0f;
constexpr float ALPHA = 10.0f;

__device__ __forceinline__ f32x4 mfma16(half8v a, half8v b, f32x4 c_) {
  return __builtin_amdgcn_mfma_f32_16x16x32_f16(a, b, c_, 0, 0, 0);
}
__device__ __forceinline__ void dma16(const void *g, void *l) {
  __builtin_amdgcn_global_load_lds(
      (const __attribute__((address_space(1))) void *)g,
      (__attribute__((address_space(3))) void *)l, 16, 0, 0);
}
template <int N> __device__ __forceinline__ void wait_vm() {
  asm volatile("s_waitcnt vmcnt(%0)" ::"n"(N) : "memory");
}

// ---- pre-split kernel: GW (64x1024 f32) and WN (64x64 f32) -> fp16 hi/lo ----
// ws image (bytes):
//   [0, 262144)        GW: 16 chunks x 16KB; chunk ck: hi[e][kk] at
//                      ck*16384 + e*128 + (((kk>>3)^(e&7))<<4) + (kk&7)*2, lo at +8192
//   [262144, 278528)   WN: same layout, single 16KB image (k = 0..63)
__global__ __launch_bounds__(256) void presplit(const float *__restrict__ GW,
                                                const float *__restrict__ WN,
                                                char *__restrict__ ws) {
  const int b = blockIdx.x;
  const int tid = threadIdx.x;
  if (b < 64) {
    int idx = b * 256 + tid;  // f32x4 index into GW
    int e = idx >> 8;
    int c4 = idx & 255;
    f32x4 v = *reinterpret_cast<const f32x4 *>(GW + (size_t)idx * 4);
#pragma unroll
    for (int j = 0; j < 4; ++j) {
      int k = c4 * 4 + j;
      float vv = v[j];
      _Float16 hh = (_Float16)vv;
      _Float16 ll = (_Float16)((vv - (float)hh) * 4096.0f);
      int ck = k >> 6, kk = k & 63;
      int off = ck * 16384 + e * 128 + ((((kk >> 3) ^ (e & 7))) << 4) + ((kk & 7) << 1);
      *reinterpret_cast<_Float16 *>(ws + off) = hh;
      *reinterpret_cast<_Float16 *>(ws + off + 8192) = ll;
    }
  } else {
    int idx = (b - 64) * 256 + tid;  // f32x4 index into WN [k][e0..e0+3]
    int k = idx >> 4;
    int e0 = (idx & 15) << 2;
    f32x4 v = *reinterpret_cast<const f32x4 *>(WN + (size_t)k * 64 + e0);
#pragma unroll
    for (int j = 0; j < 4; ++j) {
      int e = e0 + j;
      float vv = v[j];
      _Float16 hh = (_Float16)vv;
      _Float16 ll = (_Float16)((vv - (float)hh) * 4096.0f);
      int off = 262144 + e * 128 + ((((k >> 3) ^ (e & 7))) << 4) + ((k & 7) << 1);
      *reinterpret_cast<_Float16 *>(ws + off) = hh;
      *reinterpret_cast<_Float16 *>(ws + off + 8192) = ll;
    }
  }
}

// LDS map (48 KB): 3 B-buffers of 16 KB each, chunk kc lives in buf[kc%3].
// Epilogue aliases: WN image -> buf1 [16384,32768); clean tile -> buf2, wave w
// region at 32768 + w*4096.
__global__ __launch_bounds__(256, 3) void topk_gating(
    const float *__restrict__ X, const char *__restrict__ WS,
    const float *__restrict__ GB, const float *__restrict__ NZ,
    float *__restrict__ OUT) {
  __shared__ __align__(16) char lds[49152];
  const int tid = threadIdx.x;
  const int lane = tid & 63;
  const int wv = tid >> 6;
  const int q = lane >> 4;  // 0..3
  const int c = lane & 15;  // 0..15
  const int waveRow = blockIdx.x * 64 + wv * 16;

  f32x4 accH[4] = {};
  f32x4 accX[4] = {};
  f32x4 a0[4], a1[4], a2[4];  // 3 named A banks; A(kc) lives in bank kc%3

  const float *xBase = X + (size_t)(waveRow + c) * 1024 + q * 8;
  const char *wsL = WS + wv * 1024 + lane * 16;  // per-lane global src base
  char *ldsL = lds + wv * 1024;                  // DMA dest (lane off implicit)

#define LDA4(dst, p)                        \
  {                                         \
    dst[0] = *(const f32x4 *)((p) + 0);     \
    dst[1] = *(const f32x4 *)((p) + 4);     \
    dst[2] = *(const f32x4 *)((p) + 32);    \
    dst[3] = *(const f32x4 *)((p) + 36);    \
  }
#define DMAB(CK)                                                            \
  {                                                                         \
    _Pragma("unroll") for (int i_ = 0; i_ < 4; ++i_)                        \
        dma16(wsL + (CK) * 16384 + i_ * 4096,                               \
              ldsL + ((CK) % 3) * 16384 + i_ * 4096);                       \
  }
#define CONV(A, ah, al)                                           \
  {                                                               \
    _Pragma("unroll") for (int ks_ = 0; ks_ < 2; ++ks_)           \
        _Pragma("unroll") for (int j_ = 0; j_ < 8; ++j_) {        \
      float xv_ = A[ks_ * 2 + (j_ >> 2)][j_ & 3];                 \
      _Float16 hh_ = (_Float16)xv_;                               \
      ah[ks_][j_] = hh_;                                          \
      al[ks_][j_] = (_Float16)((xv_ - (float)hh_) * 4096.0f);     \
    }                                                             \
  }
#define MFMAB(BUF, ah, al)                                                 \
  {                                                                        \
    _Pragma("unroll") for (int ks_ = 0; ks_ < 2; ++ks_)                    \
        _Pragma("unroll") for (int t_ = 0; t_ < 4; ++t_) {                 \
      int e_ = t_ * 16 + c;                                                \
      int off_ = (BUF) + e_ * 128 + ((((ks_ * 4 + q) ^ (e_ & 7))) << 4);   \
      half8v bh_ = *reinterpret_cast<half8v *>(lds + off_);                \
      half8v bl_ = *reinterpret_cast<half8v *>(lds + off_ + 8192);         \
      accH[t_] = mfma16(ah[ks_], bh_, accH[t_]);                           \
      accX[t_] = mfma16(ah[ks_], bl_, accX[t_]);                           \
      accX[t_] = mfma16(al[ks_], bh_, accX[t_]);                           \
    }                                                                      \
  }
// One K-step. Issues B(KC+2) and A(KC+3) (when they exist) BEFORE the MFMA
// block; the following counted vmcnt drains exactly through B(KC+1), keeping
// the 12 youngest ops (A+2, B+1 chunks) in flight across the barrier.
#define STEP(KC, ABANK)                                          \
  {                                                              \
    half8v ah[2], al[2];                                         \
    CONV(ABANK, ah, al);                                         \
    if ((KC) + 2 <= 15) DMAB((KC) + 2);                          \
    if ((KC) + 3 <= 15) LDA4(ABANK, xBase + ((KC) + 3) * 64);    \
    MFMAB(((KC) % 3) * 16384, ah, al);                           \
  }
#define BAR() __builtin_amdgcn_s_barrier()

  // prologue: B0->buf0, B1->buf1, A0..A2 into banks; publish buf0 only
  DMAB(0);
  DMAB(1);
  LDA4(a0, xBase);
  LDA4(a1, xBase + 64);
  LDA4(a2, xBase + 128);
  wait_vm<16>();  // drains B0; leaves B1,A0,A1,A2 in flight
  BAR();

  STEP(0, a0)  wait_vm<12>(); BAR();
  STEP(1, a1)  wait_vm<12>(); BAR();
  STEP(2, a2)  wait_vm<12>(); BAR();
  STEP(3, a0)  wait_vm<12>(); BAR();
  STEP(4, a1)  wait_vm<12>(); BAR();
  STEP(5, a2)  wait_vm<12>(); BAR();
  STEP(6, a0)  wait_vm<12>(); BAR();
  STEP(7, a1)  wait_vm<12>(); BAR();
  STEP(8, a2)  wait_vm<12>(); BAR();
  STEP(9, a0)  wait_vm<12>(); BAR();
  STEP(10, a1) wait_vm<12>(); BAR();
  STEP(11, a2) wait_vm<12>(); BAR();
  STEP(12, a0) wait_vm<12>(); BAR();
  STEP(13, a1) wait_vm<8>();  BAR();  // drains B14; leaves A15,B15
  STEP(14, a2) wait_vm<0>();  BAR();  // last publish (buf0 = B15)
  STEP(15, a0)                        // no barrier: epilogue targets buf1/buf2

  // ---- epilogue ----
  // issue order (pinned): GB(4), WN-DMA(4) | fence | NZ(16)
  float bs0 = GB[c], bs1 = GB[16 + c], bs2 = GB[32 + c], bs3 = GB[48 + c];
#pragma unroll
  for (int i = 0; i < 4; ++i)
    dma16(wsL + 262144 + i * 4096, ldsL + 16384 + i * 4096);  // WN -> buf1
  asm volatile("" ::: "memory");
  float nz[4][4];
#pragma unroll
  for (int t = 0; t < 4; ++t)
#pragma unroll
    for (int r = 0; r < 4; ++r)
      nz[t][r] = NZ[(size_t)(waveRow + 4 * q + r) * 64 + t * 16 + c];

  float cl[4][4];  // [etile][reg]; element = (row 4q+r, expert 16t+c)
  const float bsv[4] = {bs0, bs1, bs2, bs3};
#pragma unroll
  for (int t = 0; t < 4; ++t)
#pragma unroll
    for (int r = 0; r < 4; ++r)
      cl[t][r] = accH[t][r] + accX[t][r] * INV4096 + bsv[t];

  // clean tile -> own-wave region of buf2, swizzled
  char *cb = lds + 32768 + wv * 4096;
#pragma unroll
  for (int t = 0; t < 4; ++t)
#pragma unroll
    for (int r = 0; r < 4; ++r) {
      int row = 4 * q + r;
      int colf = t * 16 + c;
      int off = row * 256 + ((((colf >> 2) ^ row)) << 4) + ((colf & 3) << 2);
      *reinterpret_cast<float *>(cb + off) = cl[t][r];
    }
  wait_vm<16>();  // drains GB+WN; NZ(16) stays in flight
  BAR();

  // phase 2: raw = clean @ w_noise (split-fp16 MFMA, K=64); WN image in buf1
  f32x4 rH[4] = {};
  f32x4 rX[4] = {};
#pragma unroll
  for (int ks = 0; ks < 2; ++ks) {
    int slot0 = ks * 8 + q * 2;
    f32x4 va = *reinterpret_cast<f32x4 *>(cb + c * 256 + (((slot0 ^ c)) << 4));
    f32x4 vb = *reinterpret_cast<f32x4 *>(cb + c * 256 + ((((slot0 + 1) ^ c)) << 4));
    half8v ah, al;
#pragma unroll
    for (int j = 0; j < 4; ++j) {
      float v = va[j];
      _Float16 hh = (_Float16)v;
      ah[j] = hh;
      al[j] = (_Float16)((v - (float)hh) * 4096.0f);
      float v2 = vb[j];
      _Float16 h2 = (_Float16)v2;
      ah[4 + j] = h2;
      al[4 + j] = (_Float16)((v2 - (float)h2) * 4096.0f);
    }
#pragma unroll
    for (int t = 0; t < 4; ++t) {
      int e = t * 16 + c;
      int off = 16384 + e * 128 + ((((ks * 4 + q) ^ (e & 7))) << 4);
      half8v bh = *reinterpret_cast<half8v *>(lds + off);
      half8v bl = *reinterpret_cast<half8v *>(lds + off + 8192);
      rH[t] = mfma16(ah, bh, rH[t]);
      rX[t] = mfma16(ah, bl, rX[t]);
      rX[t] = mfma16(al, bh, rX[t]);
    }
  }

  float lg[4][4];  // [r][t]
#pragma unroll
  for (int t = 0; t < 4; ++t)
#pragma unroll
    for (int r = 0; r < 4; ++r) {
      float raw = rH[t][r] + rX[t][r] * INV4096;
      float sp = fmaxf(raw, 0.0f) + __logf(1.0f + __expf(-fabsf(raw)));
      lg[r][t] = cl[t][r] + nz[t][r] * (sp + 1e-5f);
    }

#pragma unroll
  for (int r = 0; r < 4; ++r) {
    float v0 = lg[r][0], v1 = lg[r][1], v2 = lg[r][2], v3 = lg[r][3];
    // top-2: in-lane over 4, then xor-shuffle over the 16-lane group
    float a = fmaxf(v0, v1), b_ = fminf(v0, v1);
    float d1 = fmaxf(v2, v3), d2 = fminf(v2, v3);
    float m1 = fmaxf(a, d1);
    float m2 = fmaxf(fminf(a, d1), fmaxf(b_, d2));
#pragma unroll
    for (int s = 1; s <= 8; s <<= 1) {
      float om1 = __shfl_xor(m1, s, 64);
      float om2 = __shfl_xor(m2, s, 64);
      float hi = fmaxf(m1, om1);
      float lo = fminf(m1, om1);
      float sec = (m1 >= om1) ? m2 : om2;
      m2 = fmaxf(lo, sec);
      m1 = hi;
    }
    // softmax(logits)
    float se[4], ssum = 0.f;
#pragma unroll
    for (int t = 0; t < 4; ++t) {
      se[t] = __expf(lg[r][t] - m1);
      ssum += se[t];
    }
#pragma unroll
    for (int s = 1; s <= 8; s <<= 1) ssum += __shfl_xor(ssum, s, 64);
    float inv = 1.0f / ssum;
    float ov[4];
#pragma unroll
    for (int t = 0; t < 4; ++t) {
      float sm = se[t] * inv;
      float vlog = ALPHA * __logf(1.0f + sm);
      float vexp = ALPHA * (__expf(sm) - 1.0f);
      ov[t] = (lg[r][t] < m2) ? vlog : vexp;
    }
    // gates = softmax(out)
    float g = fmaxf(fmaxf(ov[0], ov[1]), fmaxf(ov[2], ov[3]));
#pragma unroll
    for (int s = 1; s <= 8; s <<= 1) g = fmaxf(g, __shfl_xor(g, s, 64));
    float gsum = 0.f;
#pragma unroll
    for (int t = 0; t < 4; ++t) {
      ov[t] = __expf(ov[t] - g);
      gsum += ov[t];
    }
#pragma unroll
    for (int s = 1; s <= 8; s <<= 1) gsum += __shfl_xor(gsum, s, 64);
    float ginv = 1.0f / gsum;
    size_t rowOff = (size_t)(waveRow + 4 * q + r) * 64;
#pragma unroll
    for (int t = 0; t < 4; ++t)
      OUT[rowOff + t * 16 + c] = ov[t] * ginv;
  }
}

extern "C" void kernel_launch(void *const *d_in, const int *in_sizes, int n_in,
                              void *d_out, int out_size, void *d_ws,
                              size_t ws_size, hipStream_t stream) {
  const float *x = (const float *)d_in[0];
  const float *gw = (const float *)d_in[1];
  const float *gb = (const float *)d_in[2];
  const float *wn = (const float *)d_in[3];
  const float *nz = (const float *)d_in[4];
  float *out = (float *)d_out;
  char *ws = (char *)d_ws;
  const int N = in_sizes[0] / 1024;

  hipLaunchKernelGGL(presplit, dim3(68), dim3(256), 0, stream, gw, wn, ws);
  hipLaunchKernelGGL(topk_gating, dim3(N / 64), dim3(256), 0, stream, x, ws,
                     gb, nz, out);
}